// Round 1
// baseline (214.031 us; speedup 1.0000x reference)
//
#include <hip/hip_runtime.h>
#include <stdint.h>

// EdgeAwareMultiHeadAttention on MI355X (gfx950)
// Pipeline:
//   k0a: fp32->bf16 conversion of x, Wq,Wk,Wv,Wo (RNE)
//   k0b: edge-MLP coefficient precompute (affine + |.| "crossing" terms)
//   k1 : fused QKV NT-GEMM (bf16 MFMA, fp32 acc, bias + Q*scale fused),
//        writes q,k,v as (B,H,N,64) bf16
//   k1b: V transpose -> (B,H,64,N) bf16 (for PV MFMA B-operand contiguity)
//   k2 : flash attention per (i-tile, head, batch) with fused edge bias,
//        no-max online softmax (logits provably bounded), writes (B,N,512) bf16
//   k3 : output NT-GEMM + bias, fp32 out

#define SEQ 2048
#define EMB 512
#define NH  8
#define HD  64
#define NB  2

typedef unsigned int   u32;
typedef unsigned short u16;
typedef u32   u32x4  __attribute__((ext_vector_type(4)));
typedef float f32x4  __attribute__((ext_vector_type(4)));
typedef __bf16 bf16x8 __attribute__((ext_vector_type(8)));

#define MFMA16(a, b, c) __builtin_amdgcn_mfma_f32_16x16x32_bf16((a), (b), (c), 0, 0, 0)

static __device__ __forceinline__ u16 f2bf(float f) {   // RNE fp32->bf16
  u32 u = __builtin_bit_cast(u32, f);
  return (u16)((u + 0x7fffu + ((u >> 16) & 1u)) >> 16);
}
static __device__ __forceinline__ bf16x8 ldfrag(const u16* p) {
  return __builtin_bit_cast(bf16x8, *(const u32x4*)p);
}

// ---------------------------------------------------------------- k0a
__global__ void cvt_bf16_kernel(const float* __restrict__ s, u16* __restrict__ d, int n) {
  int i = (blockIdx.x * blockDim.x + threadIdx.x) * 4;
  if (i >= n) return;
  float4 v = *(const float4*)(s + i);
  u32 lo = (u32)f2bf(v.x) | ((u32)f2bf(v.y) << 16);
  u32 hi = (u32)f2bf(v.z) | ((u32)f2bf(v.w) << 16);
  *(uint2*)(d + i) = make_uint2(lo, hi);
}

// ---------------------------------------------------------------- k0b
// For a in [0,1): f_h(a) = co[h] + co[8+h]*a + sum_{t<m} co[49+t*8+h]*|co[17+t]*a + co[33+t]|
// relu(u) = 0.5*(u+|u|); lines with no sign change on [0,1) fold into the affine part.
__global__ void edge_coeff_kernel(const float* __restrict__ We1, const float* __restrict__ be1,
                                  const float* __restrict__ We2, const float* __restrict__ be2,
                                  const float* __restrict__ ebias, float* __restrict__ co) {
  if (threadIdx.x != 0 || blockIdx.x != 0) return;
  float A[NH], Bc[NH];
  for (int h = 0; h < NH; h++) { A[h] = be2[h]; Bc[h] = ebias[h]; }
  int m = 0;
  for (int e = 0; e < 16; e++) {
    float w1 = We1[e], b1 = be1[e];
    float u0 = b1, u1 = w1 + b1;
    if (u0 >= 0.0f && u1 >= 0.0f) {                       // relu always on
      for (int h = 0; h < NH; h++) { float w2 = We2[h*16+e]; A[h] += w2*b1; Bc[h] += w2*w1; }
    } else if (u0 <= 0.0f && u1 <= 0.0f) {                // always off
    } else {                                              // crossing
      for (int h = 0; h < NH; h++) {
        float w2 = We2[h*16+e];
        A[h]  += 0.5f*w2*b1;
        Bc[h] += 0.5f*w2*w1;
        co[49 + m*8 + h] = 0.5f*w2;
      }
      co[17+m] = w1; co[33+m] = b1; m++;
    }
  }
  for (int h = 0; h < NH; h++) { co[h] = A[h]; co[8+h] = Bc[h]; }
  ((int*)co)[16] = m;
}

// ---------------------------------------------------------------- k1: QKV GEMM
// C[row,col] = sum_k xb[row,k]*Wqkv[col,k]; 128x128 tile, BK=32, 4 waves 2x2.
#define LDA 40   // u16 per LDS row (32 data + 8 pad) -> 80B row stride, 16B aligned
__global__ __launch_bounds__(256) void gemm_qkv_kernel(
    const u16* __restrict__ A, const u16* __restrict__ Bm,
    const float* __restrict__ bq, const float* __restrict__ bk, const float* __restrict__ bv,
    u16* __restrict__ qh, u16* __restrict__ kh, u16* __restrict__ vh)
{
  __shared__ u16 As[128 * LDA];
  __shared__ u16 Bs[128 * LDA];
  const int tid = threadIdx.x;
  const int lane = tid & 63, wid = tid >> 6;
  const int q = lane >> 4, l15 = lane & 15;
  const int m0 = blockIdx.y * 128;
  const int n0 = blockIdx.x * 128;
  const int wh = wid >> 1, ww = wid & 1;

  f32x4 acc[4][4];
  f32x4 zero = {0.f, 0.f, 0.f, 0.f};
  #pragma unroll
  for (int i = 0; i < 4; i++)
    #pragma unroll
    for (int j = 0; j < 4; j++) acc[i][j] = zero;

  const int srow = tid >> 1, shalf = tid & 1;
  const u16* ga = A  + (size_t)(m0 + srow) * EMB + shalf * 16;
  const u16* gb = Bm + (size_t)(n0 + srow) * EMB + shalf * 16;
  u16* la = &As[srow * LDA + shalf * 16];
  u16* lb = &Bs[srow * LDA + shalf * 16];

  for (int k0 = 0; k0 < EMB; k0 += 32) {
    __syncthreads();
    u32x4 a0 = *(const u32x4*)(ga);
    u32x4 a1 = *(const u32x4*)(ga + 8);
    u32x4 b0 = *(const u32x4*)(gb);
    u32x4 b1 = *(const u32x4*)(gb + 8);
    ga += 32; gb += 32;
    *(u32x4*)(la)     = a0; *(u32x4*)(la + 8) = a1;
    *(u32x4*)(lb)     = b0; *(u32x4*)(lb + 8) = b1;
    __syncthreads();
    bf16x8 af[4], bfr[4];
    #pragma unroll
    for (int mi = 0; mi < 4; mi++)
      af[mi] = ldfrag(&As[(wh*64 + mi*16 + l15) * LDA + q*8]);
    #pragma unroll
    for (int ni = 0; ni < 4; ni++)
      bfr[ni] = ldfrag(&Bs[(ww*64 + ni*16 + l15) * LDA + q*8]);
    #pragma unroll
    for (int mi = 0; mi < 4; mi++)
      #pragma unroll
      for (int ni = 0; ni < 4; ni++)
        acc[mi][ni] = MFMA16(af[mi], bfr[ni], acc[mi][ni]);
  }

  const int mat = n0 >> 9;                // 0:Q 1:K 2:V (128-col tile never crosses)
  const float* bias = (mat == 0) ? bq : ((mat == 1) ? bk : bv);
  u16* dst = (mat == 0) ? qh : ((mat == 1) ? kh : vh);
  const float mul = (mat == 0) ? 0.125f : 1.0f;   // fold scale=1/sqrt(64) into Q (incl bias)

  #pragma unroll
  for (int mi = 0; mi < 4; mi++) {
    int rowb = m0 + wh*64 + mi*16 + q*4;
    #pragma unroll
    for (int ni = 0; ni < 4; ni++) {
      int col = n0 + ww*64 + ni*16 + l15;
      int oo = col & 511;
      float bsv = bias[oo];
      int h = oo >> 6, dd = oo & 63;
      #pragma unroll
      for (int r = 0; r < 4; r++) {
        int grow = rowb + r;
        int b_ = grow >> 11, n_ = grow & 2047;
        float val = (acc[mi][ni][r] + bsv) * mul;
        dst[((size_t)(b_ * NH + h) * SEQ + n_) * HD + dd] = f2bf(val);
      }
    }
  }
}

// ---------------------------------------------------------------- k3: out GEMM
__global__ __launch_bounds__(256) void gemm_out_kernel(
    const u16* __restrict__ A, const u16* __restrict__ Bm,
    const float* __restrict__ bo, float* __restrict__ out)
{
  __shared__ u16 As[128 * LDA];
  __shared__ u16 Bs[128 * LDA];
  const int tid = threadIdx.x;
  const int lane = tid & 63, wid = tid >> 6;
  const int q = lane >> 4, l15 = lane & 15;
  const int m0 = blockIdx.y * 128;
  const int n0 = blockIdx.x * 128;
  const int wh = wid >> 1, ww = wid & 1;

  f32x4 acc[4][4];
  f32x4 zero = {0.f, 0.f, 0.f, 0.f};
  #pragma unroll
  for (int i = 0; i < 4; i++)
    #pragma unroll
    for (int j = 0; j < 4; j++) acc[i][j] = zero;

  const int srow = tid >> 1, shalf = tid & 1;
  const u16* ga = A  + (size_t)(m0 + srow) * EMB + shalf * 16;
  const u16* gb = Bm + (size_t)(n0 + srow) * EMB + shalf * 16;
  u16* la = &As[srow * LDA + shalf * 16];
  u16* lb = &Bs[srow * LDA + shalf * 16];

  for (int k0 = 0; k0 < EMB; k0 += 32) {
    __syncthreads();
    u32x4 a0 = *(const u32x4*)(ga);
    u32x4 a1 = *(const u32x4*)(ga + 8);
    u32x4 b0 = *(const u32x4*)(gb);
    u32x4 b1 = *(const u32x4*)(gb + 8);
    ga += 32; gb += 32;
    *(u32x4*)(la)     = a0; *(u32x4*)(la + 8) = a1;
    *(u32x4*)(lb)     = b0; *(u32x4*)(lb + 8) = b1;
    __syncthreads();
    bf16x8 af[4], bfr[4];
    #pragma unroll
    for (int mi = 0; mi < 4; mi++)
      af[mi] = ldfrag(&As[(wh*64 + mi*16 + l15) * LDA + q*8]);
    #pragma unroll
    for (int ni = 0; ni < 4; ni++)
      bfr[ni] = ldfrag(&Bs[(ww*64 + ni*16 + l15) * LDA + q*8]);
    #pragma unroll
    for (int mi = 0; mi < 4; mi++)
      #pragma unroll
      for (int ni = 0; ni < 4; ni++)
        acc[mi][ni] = MFMA16(af[mi], bfr[ni], acc[mi][ni]);
  }

  #pragma unroll
  for (int mi = 0; mi < 4; mi++) {
    int rowb = m0 + wh*64 + mi*16 + q*4;
    #pragma unroll
    for (int ni = 0; ni < 4; ni++) {
      int col = n0 + ww*64 + ni*16 + l15;
      float bsv = bo[col];
      #pragma unroll
      for (int r = 0; r < 4; r++)
        out[(size_t)(rowb + r) * EMB + col] = acc[mi][ni][r] + bsv;
    }
  }
}

// ---------------------------------------------------------------- k1b: V transpose
__global__ __launch_bounds__(256) void vtrans_kernel(const u16* __restrict__ vh, u16* __restrict__ vt) {
  __shared__ u16 Ts[64 * 72];
  const int b = blockIdx.z, h = blockIdx.y, j0 = blockIdx.x * 64;
  const int t = threadIdx.x;
  const u16* src = vh + ((size_t)(b * NH + h) * SEQ + j0) * HD;
  {
    int r = t >> 2, c = t & 3;
    *(u32x4*)&Ts[r*72 + c*16]     = *(const u32x4*)(src + r*HD + c*16);
    *(u32x4*)&Ts[r*72 + c*16 + 8] = *(const u32x4*)(src + r*HD + c*16 + 8);
  }
  __syncthreads();
  int d = t >> 2, jc = t & 3;
  u32 w[8];
  #pragma unroll
  for (int p = 0; p < 8; p++) {
    u32 lo = Ts[(jc*16 + 2*p    ) * 72 + d];
    u32 hi = Ts[(jc*16 + 2*p + 1) * 72 + d];
    w[p] = lo | (hi << 16);
  }
  u16* dst = vt + ((size_t)(b * NH + h) * HD + d) * SEQ + j0 + jc * 16;
  u32x4 w0 = {w[0], w[1], w[2], w[3]};
  u32x4 w1 = {w[4], w[5], w[6], w[7]};
  *(u32x4*)(dst)     = w0;
  *(u32x4*)(dst + 8) = w1;
}

// ---------------------------------------------------------------- k2: flash + edge
// block = (i-tile of 64 rows, head, batch); 4 waves, wave w owns rows w*16..w*16+15.
// grid.x = i-tile so all 8 heads of one i-tile land on one XCD (adjacency L2 reuse).
__global__ __launch_bounds__(256) void flash_kernel(
    const u16* __restrict__ qh, const u16* __restrict__ kh, const u16* __restrict__ vt,
    const float* __restrict__ adj, const float* __restrict__ coeff, u16* __restrict__ om)
{
  __shared__ u16 Ks[64 * 72];      // [j][d], 144B row stride
  __shared__ u16 Vs[64 * 72];      // [d][j]
  __shared__ u16 Ps[4 * 16 * 72];  // per-wave P tile [i][j]
  __shared__ u16 Os[64 * 72];      // [i][d]
  __shared__ float l_lds[4][16];

  const int tid = threadIdx.x, lane = tid & 63, w = tid >> 6;
  const int q = lane >> 4, l15 = lane & 15;
  const int i0 = blockIdx.x * 64;
  const int h = blockIdx.y, b = blockIdx.z;
  const int bh = b * NH + h;

  const float Ah = coeff[h], Bh = coeff[8 + h];
  const int mterms = ((const int*)coeff)[16];

  // Q fragments (scale already folded): 16 rows x 64 d, resident
  const u16* qbase = qh + ((size_t)bh * SEQ + i0 + w*16 + l15) * HD + q*8;
  bf16x8 qf0 = ldfrag(qbase);
  bf16x8 qf1 = ldfrag(qbase + 32);

  f32x4 O[4];
  f32x4 zero = {0.f, 0.f, 0.f, 0.f};
  #pragma unroll
  for (int dt = 0; dt < 4; dt++) O[dt] = zero;
  float lsum[4] = {0.f, 0.f, 0.f, 0.f};

  const u16* kgbase = kh + (size_t)bh * SEQ * HD;
  const u16* vgbase = vt + (size_t)bh * HD * SEQ;
  const float* abase = adj + ((size_t)b * SEQ + i0 + w*16 + q*4) * SEQ;

  const int sr = tid >> 2, sc = tid & 3;
  u16* psw = &Ps[w * 16 * 72];

  for (int jc = 0; jc < SEQ; jc += 64) {
    __syncthreads();
    { // stage K tile [j][d] and V^T tile [d][j]
      const u16* g = kgbase + (size_t)(jc + sr) * HD + sc * 16;
      u32x4 v0 = *(const u32x4*)g;
      u32x4 v1 = *(const u32x4*)(g + 8);
      *(u32x4*)&Ks[sr*72 + sc*16]     = v0;
      *(u32x4*)&Ks[sr*72 + sc*16 + 8] = v1;
      const u16* g2 = vgbase + (size_t)sr * SEQ + jc + sc * 16;
      u32x4 u0 = *(const u32x4*)g2;
      u32x4 u1 = *(const u32x4*)(g2 + 8);
      *(u32x4*)&Vs[sr*72 + sc*16]     = u0;
      *(u32x4*)&Vs[sr*72 + sc*16 + 8] = u1;
    }
    __syncthreads();

    // adjacency for this wave's 16x64 score tile (issue early)
    float av[4][4];
    #pragma unroll
    for (int jt = 0; jt < 4; jt++)
      #pragma unroll
      for (int r = 0; r < 4; r++)
        av[jt][r] = abase[(size_t)r * SEQ + jc + jt*16 + l15];

    // S = Q K^T (fp32 acc, scale pre-folded)
    f32x4 S[4];
    #pragma unroll
    for (int jt = 0; jt < 4; jt++) {
      bf16x8 kf0 = ldfrag(&Ks[(jt*16 + l15) * 72 + q*8]);
      bf16x8 kf1 = ldfrag(&Ks[(jt*16 + l15) * 72 + 32 + q*8]);
      f32x4 s = zero;
      s = MFMA16(qf0, kf0, s);
      s = MFMA16(qf1, kf1, s);
      S[jt] = s;
    }

    // edge bias: affine + crossing |.| terms
    float eb[4][4];
    #pragma unroll
    for (int jt = 0; jt < 4; jt++)
      #pragma unroll
      for (int r = 0; r < 4; r++)
        eb[jt][r] = fmaf(av[jt][r], Bh, Ah);
    for (int t = 0; t < mterms; t++) {
      float ct = coeff[17 + t], dt_ = coeff[33 + t], wt = coeff[49 + t*8 + h];
      #pragma unroll
      for (int jt = 0; jt < 4; jt++)
        #pragma unroll
        for (int r = 0; r < 4; r++)
          eb[jt][r] = fmaf(fabsf(fmaf(av[jt][r], ct, dt_)), wt, eb[jt][r]);
    }

    // p = exp(S + edge)  (no max-sub: logits bounded well under exp overflow)
    #pragma unroll
    for (int jt = 0; jt < 4; jt++) {
      #pragma unroll
      for (int r = 0; r < 4; r++) {
        float p = __expf(S[jt][r] + eb[jt][r]);
        lsum[r] += p;
        psw[(q*4 + r) * 72 + jt*16 + l15] = f2bf(p);
      }
    }

    // O^T += V^T P^T  (same-wave LDS write->read, DS ops in-order)
    bf16x8 pf0 = ldfrag(&psw[l15 * 72 + q*8]);
    bf16x8 pf1 = ldfrag(&psw[l15 * 72 + 32 + q*8]);
    #pragma unroll
    for (int dt = 0; dt < 4; dt++) {
      bf16x8 vf0 = ldfrag(&Vs[(dt*16 + l15) * 72 + q*8]);
      bf16x8 vf1 = ldfrag(&Vs[(dt*16 + l15) * 72 + 32 + q*8]);
      O[dt] = MFMA16(vf0, pf0, O[dt]);
      O[dt] = MFMA16(vf1, pf1, O[dt]);
    }
  }

  // row sums: reduce over the 16 lanes of each quad-group
  #pragma unroll
  for (int r = 0; r < 4; r++) {
    float v = lsum[r];
    v += __shfl_xor(v, 1);
    v += __shfl_xor(v, 2);
    v += __shfl_xor(v, 4);
    v += __shfl_xor(v, 8);
    l_lds[w][q*4 + r] = v;   // same value from all 16 lanes of the group
  }
  float rl = 1.0f / l_lds[w][l15];   // same-wave LDS, in-order

  // O[i][d] = O^T[d][i] / l[i] -> Os, then coalesced store to om (B,N,512)
  #pragma unroll
  for (int dt = 0; dt < 4; dt++)
    #pragma unroll
    for (int r = 0; r < 4; r++)
      Os[(w*16 + l15) * 72 + dt*16 + q*4 + r] = f2bf(O[dt][r] * rl);
  __syncthreads();
  {
    int orow = tid >> 2, oc = tid & 3;
    u32x4 o0 = *(const u32x4*)&Os[orow*72 + oc*16];
    u32x4 o1 = *(const u32x4*)&Os[orow*72 + oc*16 + 8];
    u16* dst = om + ((size_t)b * SEQ + i0 + orow) * EMB + h * HD + oc * 16;
    *(u32x4*)(dst)     = o0;
    *(u32x4*)(dst + 8) = o1;
  }
}

// ---------------------------------------------------------------- launch
extern "C" void kernel_launch(void* const* d_in, const int* in_sizes, int n_in,
                              void* d_out, int out_size, void* d_ws, size_t ws_size,
                              hipStream_t stream) {
  const float* x     = (const float*)d_in[0];
  const float* adj   = (const float*)d_in[1];
  const float* Wq    = (const float*)d_in[2];
  const float* bq    = (const float*)d_in[3];
  const float* Wk    = (const float*)d_in[4];
  const float* bk    = (const float*)d_in[5];
  const float* Wv    = (const float*)d_in[6];
  const float* bv    = (const float*)d_in[7];
  const float* Wo    = (const float*)d_in[8];
  const float* bo    = (const float*)d_in[9];
  const float* We1   = (const float*)d_in[10];
  const float* be1   = (const float*)d_in[11];
  const float* We2   = (const float*)d_in[12];
  const float* be2   = (const float*)d_in[13];
  const float* ebias = (const float*)d_in[14];
  float* out = (float*)d_out;

  char* ws = (char*)d_ws;
  u16*   xb   = (u16*)(ws + 0);          //  4 MB  x bf16
  u16*   wqkv = (u16*)(ws + 4194304);    //  1.5MB Wq|Wk|Wv bf16 (contiguous [1536][512])
  u16*   wob  = (u16*)(ws + 5767168);    //  0.5MB Wo bf16
  u16*   qh   = (u16*)(ws + 6291456);    //  4 MB  (B,H,N,64)
  u16*   kh   = (u16*)(ws + 10485760);   //  4 MB
  u16*   vh   = (u16*)(ws + 14680064);   //  4 MB
  u16*   vt   = (u16*)(ws + 18874368);   //  4 MB  (B,H,64,N)
  u16*   om   = (u16*)(ws + 23068672);   //  4 MB  (B,N,512)
  float* co   = (float*)(ws + 27262976); //  1 KB  edge coefficients
  if (ws_size < 27264000) return;

  cvt_bf16_kernel<<<2048, 256, 0, stream>>>(x, xb, NB * SEQ * EMB);
  cvt_bf16_kernel<<<256, 256, 0, stream>>>(Wq, wqkv + 0 * EMB * EMB, EMB * EMB);
  cvt_bf16_kernel<<<256, 256, 0, stream>>>(Wk, wqkv + 1 * EMB * EMB, EMB * EMB);
  cvt_bf16_kernel<<<256, 256, 0, stream>>>(Wv, wqkv + 2 * EMB * EMB, EMB * EMB);
  cvt_bf16_kernel<<<256, 256, 0, stream>>>(Wo, wob, EMB * EMB);
  edge_coeff_kernel<<<1, 64, 0, stream>>>(We1, be1, We2, be2, ebias, co);
  gemm_qkv_kernel<<<dim3(12, 32), 256, 0, stream>>>(xb, wqkv, bq, bk, bv, qh, kh, vh);
  vtrans_kernel<<<dim3(32, NH, NB), 256, 0, stream>>>(vh, vt);
  flash_kernel<<<dim3(32, NH, NB), 256, 0, stream>>>(qh, kh, vt, adj, co, om);
  gemm_out_kernel<<<dim3(4, 32), 256, 0, stream>>>(om, wob, bo, out);
}

// Round 2
// 199.723 us; speedup vs baseline: 1.0716x; 1.0716x over previous
//
#include <hip/hip_runtime.h>
#include <stdint.h>

// EdgeAwareMultiHeadAttention on MI355X (gfx950) — round 2
// Changes vs round 1:
//  * edge_coeff: 1 thread -> 128 threads (was ~60us of serial load latency)
//  * flash: register-prefetch pipeline for K/V + adjacency (t+1 issued during t),
//           O computed directly (P as MFMA A-operand) -> no Os buffer, no l_lds,
//           LDS 37.4KB -> 27.6KB
//  * both GEMMs: register-prefetch pipeline on the k-loop
//  * gemm_out: 64x128 tiles, 256 blocks (was 128 -> half the GPU idle)
//  * 4 weight-conversion launches merged into 1

#define SEQ 2048
#define EMB 512
#define NH  8
#define HD  64
#define NB  2

typedef unsigned int   u32;
typedef unsigned short u16;
typedef u32   u32x4  __attribute__((ext_vector_type(4)));
typedef float f32x4  __attribute__((ext_vector_type(4)));
typedef __bf16 bf16x8 __attribute__((ext_vector_type(8)));

#define MFMA16(a, b, c) __builtin_amdgcn_mfma_f32_16x16x32_bf16((a), (b), (c), 0, 0, 0)

static __device__ __forceinline__ u16 f2bf(float f) {   // RNE fp32->bf16
  u32 u = __builtin_bit_cast(u32, f);
  return (u16)((u + 0x7fffu + ((u >> 16) & 1u)) >> 16);
}
static __device__ __forceinline__ bf16x8 ldfrag(const u16* p) {
  return __builtin_bit_cast(bf16x8, *(const u32x4*)p);
}

// ---------------------------------------------------------------- k0a: x -> bf16
__global__ void cvt_bf16_kernel(const float* __restrict__ s, u16* __restrict__ d, int n) {
  int i = (blockIdx.x * blockDim.x + threadIdx.x) * 4;
  if (i >= n) return;
  float4 v = *(const float4*)(s + i);
  u32 lo = (u32)f2bf(v.x) | ((u32)f2bf(v.y) << 16);
  u32 hi = (u32)f2bf(v.z) | ((u32)f2bf(v.w) << 16);
  *(uint2*)(d + i) = make_uint2(lo, hi);
}

// ---------------------------------------------------------------- k0a': all W -> bf16 (one launch)
__global__ void cvt_w_kernel(const float* __restrict__ Wq, const float* __restrict__ Wk,
                             const float* __restrict__ Wv, const float* __restrict__ Wo,
                             u16* __restrict__ wqkv, u16* __restrict__ wob) {
  int i = (blockIdx.x * blockDim.x + threadIdx.x) * 4;   // 4 * 262144 total elems
  int m = i >> 18;
  int off = i & 262143;
  const float* src = (m == 0) ? Wq : ((m == 1) ? Wk : ((m == 2) ? Wv : Wo));
  u16* dst = (m < 3) ? (wqkv + (size_t)m * 262144) : wob;
  float4 v = *(const float4*)(src + off);
  u32 lo = (u32)f2bf(v.x) | ((u32)f2bf(v.y) << 16);
  u32 hi = (u32)f2bf(v.z) | ((u32)f2bf(v.w) << 16);
  *(uint2*)(dst + off) = make_uint2(lo, hi);
}

// ---------------------------------------------------------------- k0b: edge coeffs (parallel)
// f_h(a) = co[h] + co[8+h]*a + sum_{t<m} co[49+t*8+h]*|co[17+t]*a + co[33+t]|, a in [0,1)
__global__ void edge_coeff_kernel(const float* __restrict__ We1, const float* __restrict__ be1,
                                  const float* __restrict__ We2, const float* __restrict__ be2,
                                  const float* __restrict__ ebias, float* __restrict__ co) {
  const int t = threadIdx.x;        // 128 threads: e = t&15, h = t>>4 (two waves)
  const int e = t & 15, h = t >> 4;
  float w1 = We1[e], b1 = be1[e], w2 = We2[h * 16 + e];
  float u0 = b1, u1 = w1 + b1;
  bool on  = (u0 >= 0.0f) && (u1 >= 0.0f);
  bool off = (u0 <= 0.0f) && (u1 <= 0.0f);
  bool crossing = (!on) && (!off);
  float ca = on ? (w2 * b1) : (crossing ? 0.5f * w2 * b1 : 0.0f);
  float cb = on ? (w2 * w1) : (crossing ? 0.5f * w2 * w1 : 0.0f);
  // reduce over e within each 16-lane h-group
  #pragma unroll
  for (int d = 1; d < 16; d <<= 1) {
    ca += __shfl_xor(ca, d);
    cb += __shfl_xor(cb, d);
  }
  if (e == 0) { co[h] = be2[h] + ca; co[8 + h] = ebias[h] + cb; }
  unsigned long long msk = __ballot(crossing);   // same 16-bit pattern replicated per h-group
  int midx = __popcll(msk & 0xFFFFull & ((1ull << e) - 1ull));
  int mcnt = __popcll(msk & 0xFFFFull);
  if (crossing) {
    co[49 + midx * 8 + h] = 0.5f * w2;
    if (h == 0 || h == 4) { /* one writer per wave is enough; duplicates identical */ }
    if (h == 0) { co[17 + midx] = w1; co[33 + midx] = b1; }
  }
  if (t == 0) ((int*)co)[16] = mcnt;
}

// ---------------------------------------------------------------- k1: QKV GEMM (pipelined)
#define LDA 40   // u16 per LDS row (32 data + 8 pad), 16B aligned
__global__ __launch_bounds__(256) void gemm_qkv_kernel(
    const u16* __restrict__ A, const u16* __restrict__ Bm,
    const float* __restrict__ bq, const float* __restrict__ bk, const float* __restrict__ bv,
    u16* __restrict__ qh, u16* __restrict__ kh, u16* __restrict__ vh)
{
  __shared__ u16 As[128 * LDA];
  __shared__ u16 Bs[128 * LDA];
  const int tid = threadIdx.x;
  const int lane = tid & 63, wid = tid >> 6;
  const int q = lane >> 4, l15 = lane & 15;
  const int m0 = blockIdx.y * 128;
  const int n0 = blockIdx.x * 128;
  const int wh = wid >> 1, ww = wid & 1;

  f32x4 acc[4][4];
  f32x4 zero = {0.f, 0.f, 0.f, 0.f};
  #pragma unroll
  for (int i = 0; i < 4; i++)
    #pragma unroll
    for (int j = 0; j < 4; j++) acc[i][j] = zero;

  const int srow = tid >> 1, shalf = tid & 1;
  const u16* ga = A  + (size_t)(m0 + srow) * EMB + shalf * 16;
  const u16* gb = Bm + (size_t)(n0 + srow) * EMB + shalf * 16;
  u16* la = &As[srow * LDA + shalf * 16];
  u16* lb = &Bs[srow * LDA + shalf * 16];

  // prologue: prefetch k-tile 0
  u32x4 pa0 = *(const u32x4*)(ga);
  u32x4 pa1 = *(const u32x4*)(ga + 8);
  u32x4 pb0 = *(const u32x4*)(gb);
  u32x4 pb1 = *(const u32x4*)(gb + 8);
  ga += 32; gb += 32;

  for (int k0 = 0; k0 < EMB; k0 += 32) {
    __syncthreads();
    *(u32x4*)(la)     = pa0; *(u32x4*)(la + 8) = pa1;
    *(u32x4*)(lb)     = pb0; *(u32x4*)(lb + 8) = pb1;
    __syncthreads();
    if (k0 + 32 < EMB) {       // prefetch next k-tile during compute
      pa0 = *(const u32x4*)(ga);
      pa1 = *(const u32x4*)(ga + 8);
      pb0 = *(const u32x4*)(gb);
      pb1 = *(const u32x4*)(gb + 8);
      ga += 32; gb += 32;
    }
    bf16x8 af[4], bfr[4];
    #pragma unroll
    for (int mi = 0; mi < 4; mi++)
      af[mi] = ldfrag(&As[(wh*64 + mi*16 + l15) * LDA + q*8]);
    #pragma unroll
    for (int ni = 0; ni < 4; ni++)
      bfr[ni] = ldfrag(&Bs[(ww*64 + ni*16 + l15) * LDA + q*8]);
    #pragma unroll
    for (int mi = 0; mi < 4; mi++)
      #pragma unroll
      for (int ni = 0; ni < 4; ni++)
        acc[mi][ni] = MFMA16(af[mi], bfr[ni], acc[mi][ni]);
  }

  const int mat = n0 >> 9;                // 0:Q 1:K 2:V
  const float* bias = (mat == 0) ? bq : ((mat == 1) ? bk : bv);
  u16* dst = (mat == 0) ? qh : ((mat == 1) ? kh : vh);
  const float mul = (mat == 0) ? 0.125f : 1.0f;   // fold scale into Q

  #pragma unroll
  for (int mi = 0; mi < 4; mi++) {
    int rowb = m0 + wh*64 + mi*16 + q*4;
    #pragma unroll
    for (int ni = 0; ni < 4; ni++) {
      int col = n0 + ww*64 + ni*16 + l15;
      int oo = col & 511;
      float bsv = bias[oo];
      int h = oo >> 6, dd = oo & 63;
      #pragma unroll
      for (int r = 0; r < 4; r++) {
        int grow = rowb + r;
        int b_ = grow >> 11, n_ = grow & 2047;
        float val = (acc[mi][ni][r] + bsv) * mul;
        dst[((size_t)(b_ * NH + h) * SEQ + n_) * HD + dd] = f2bf(val);
      }
    }
  }
}

// ---------------------------------------------------------------- k3: out GEMM 64x128 (pipelined)
__global__ __launch_bounds__(256) void gemm_out_kernel(
    const u16* __restrict__ A, const u16* __restrict__ Bm,
    const float* __restrict__ bo, float* __restrict__ out)
{
  __shared__ u16 As[64 * LDA];
  __shared__ u16 Bs[128 * LDA];
  const int tid = threadIdx.x;
  const int lane = tid & 63, w = tid >> 6;
  const int q = lane >> 4, l15 = lane & 15;
  const int m0 = blockIdx.y * 64;
  const int n0 = blockIdx.x * 128;

  f32x4 acc[4][2];
  f32x4 zero = {0.f, 0.f, 0.f, 0.f};
  #pragma unroll
  for (int i = 0; i < 4; i++) { acc[i][0] = zero; acc[i][1] = zero; }

  // staging: waves 0,1 (tid<128) stage A (64 rows, 2 thr/row);
  //          waves 2,3 stage B (128 rows, 1 thr/row, 4 chunks)
  const bool isA = tid < 128;
  const int arow = tid >> 1, ahalf = tid & 1;
  const int brow = tid - 128;
  const u16* ga = A  + (size_t)(m0 + arow) * EMB + ahalf * 16;
  const u16* gb = Bm + (size_t)(n0 + brow) * EMB;
  u16* la = &As[arow * LDA + ahalf * 16];
  u16* lb = &Bs[brow * LDA];

  u32x4 p0, p1, p2, p3;
  if (isA) {
    p0 = *(const u32x4*)(ga);
    p1 = *(const u32x4*)(ga + 8);
    ga += 32;
  } else {
    p0 = *(const u32x4*)(gb);
    p1 = *(const u32x4*)(gb + 8);
    p2 = *(const u32x4*)(gb + 16);
    p3 = *(const u32x4*)(gb + 24);
    gb += 32;
  }

  for (int k0 = 0; k0 < EMB; k0 += 32) {
    __syncthreads();
    if (isA) {
      *(u32x4*)(la)     = p0; *(u32x4*)(la + 8) = p1;
    } else {
      *(u32x4*)(lb)      = p0; *(u32x4*)(lb + 8)  = p1;
      *(u32x4*)(lb + 16) = p2; *(u32x4*)(lb + 24) = p3;
    }
    __syncthreads();
    if (k0 + 32 < EMB) {
      if (isA) {
        p0 = *(const u32x4*)(ga);
        p1 = *(const u32x4*)(ga + 8);
        ga += 32;
      } else {
        p0 = *(const u32x4*)(gb);
        p1 = *(const u32x4*)(gb + 8);
        p2 = *(const u32x4*)(gb + 16);
        p3 = *(const u32x4*)(gb + 24);
        gb += 32;
      }
    }
    bf16x8 af[4], bfr[2];
    #pragma unroll
    for (int mi = 0; mi < 4; mi++)
      af[mi] = ldfrag(&As[(mi*16 + l15) * LDA + q*8]);
    #pragma unroll
    for (int ni = 0; ni < 2; ni++)
      bfr[ni] = ldfrag(&Bs[(w*32 + ni*16 + l15) * LDA + q*8]);
    #pragma unroll
    for (int mi = 0; mi < 4; mi++)
      #pragma unroll
      for (int ni = 0; ni < 2; ni++)
        acc[mi][ni] = MFMA16(af[mi], bfr[ni], acc[mi][ni]);
  }

  #pragma unroll
  for (int mi = 0; mi < 4; mi++) {
    int rowb = m0 + mi*16 + q*4;
    #pragma unroll
    for (int ni = 0; ni < 2; ni++) {
      int col = n0 + w*32 + ni*16 + l15;
      float bsv = bo[col];
      #pragma unroll
      for (int r = 0; r < 4; r++)
        out[(size_t)(rowb + r) * EMB + col] = acc[mi][ni][r] + bsv;
    }
  }
}

// ---------------------------------------------------------------- k1b: V transpose
__global__ __launch_bounds__(256) void vtrans_kernel(const u16* __restrict__ vh, u16* __restrict__ vt) {
  __shared__ u16 Ts[64 * 72];
  const int b = blockIdx.z, h = blockIdx.y, j0 = blockIdx.x * 64;
  const int t = threadIdx.x;
  const u16* src = vh + ((size_t)(b * NH + h) * SEQ + j0) * HD;
  {
    int r = t >> 2, c = t & 3;
    *(u32x4*)&Ts[r*72 + c*16]     = *(const u32x4*)(src + r*HD + c*16);
    *(u32x4*)&Ts[r*72 + c*16 + 8] = *(const u32x4*)(src + r*HD + c*16 + 8);
  }
  __syncthreads();
  int d = t >> 2, jc = t & 3;
  u32 wv[8];
  #pragma unroll
  for (int p = 0; p < 8; p++) {
    u32 lo = Ts[(jc*16 + 2*p    ) * 72 + d];
    u32 hi = Ts[(jc*16 + 2*p + 1) * 72 + d];
    wv[p] = lo | (hi << 16);
  }
  u16* dst = vt + ((size_t)(b * NH + h) * HD + d) * SEQ + j0 + jc * 16;
  u32x4 w0 = {wv[0], wv[1], wv[2], wv[3]};
  u32x4 w1 = {wv[4], wv[5], wv[6], wv[7]};
  *(u32x4*)(dst)     = w0;
  *(u32x4*)(dst + 8) = w1;
}

// ---------------------------------------------------------------- k2: flash + edge (pipelined)
__global__ __launch_bounds__(256) void flash_kernel(
    const u16* __restrict__ qh, const u16* __restrict__ kh, const u16* __restrict__ vt,
    const float* __restrict__ adj, const float* __restrict__ coeff, u16* __restrict__ om)
{
  __shared__ u16 Ks[64 * 72];      // [j][d]
  __shared__ u16 Vs[64 * 72];      // [d][j]
  __shared__ u16 Ps[4 * 16 * 72];  // per-wave P tile [i][j]

  const int tid = threadIdx.x, lane = tid & 63, w = tid >> 6;
  const int q = lane >> 4, l15 = lane & 15;
  const int i0 = blockIdx.x * 64;
  const int h = blockIdx.y, b = blockIdx.z;
  const int bh = b * NH + h;

  const float Ah = coeff[h], Bh = coeff[8 + h];
  const int mterms = ((const int*)coeff)[16];

  const u16* qbase = qh + ((size_t)bh * SEQ + i0 + w*16 + l15) * HD + q*8;
  bf16x8 qf0 = ldfrag(qbase);
  bf16x8 qf1 = ldfrag(qbase + 32);

  f32x4 O[4];
  f32x4 zero = {0.f, 0.f, 0.f, 0.f};
  #pragma unroll
  for (int dt = 0; dt < 4; dt++) O[dt] = zero;
  float lsum[4] = {0.f, 0.f, 0.f, 0.f};

  const u16* kgbase = kh + (size_t)bh * SEQ * HD;
  const u16* vgbase = vt + (size_t)bh * HD * SEQ;
  const float* abase = adj + ((size_t)b * SEQ + i0 + w*16 + q*4) * SEQ;

  const int sr = tid >> 2, sc = tid & 3;
  u16* psw = &Ps[w * 16 * 72];

  // ---- prologue: prefetch tile 0 into registers
  u32x4 pk0, pk1, pv0, pv1;
  float padj[16];
  {
    const u16* gk = kgbase + (size_t)sr * HD + sc * 16;
    const u16* gv = vgbase + (size_t)sr * SEQ + sc * 16;
    pk0 = *(const u32x4*)(gk);
    pk1 = *(const u32x4*)(gk + 8);
    pv0 = *(const u32x4*)(gv);
    pv1 = *(const u32x4*)(gv + 8);
    #pragma unroll
    for (int jt = 0; jt < 4; jt++)
      #pragma unroll
      for (int r = 0; r < 4; r++)
        padj[jt*4 + r] = abase[(size_t)r * SEQ + jt*16 + l15];
  }

  for (int it = 0; it < 32; it++) {
    __syncthreads();                       // previous tile's LDS readers done
    *(u32x4*)&Ks[sr*72 + sc*16]     = pk0;
    *(u32x4*)&Ks[sr*72 + sc*16 + 8] = pk1;
    *(u32x4*)&Vs[sr*72 + sc*16]     = pv0;
    *(u32x4*)&Vs[sr*72 + sc*16 + 8] = pv1;
    __syncthreads();

    const int nx = (it + 1 < 32) ? (it + 1) * 64 : 0;   // clamped (harmless) prefetch

    // issue next K/V prefetch immediately — consumed at next iter's LDS write
    {
      const u16* gk = kgbase + (size_t)(nx + sr) * HD + sc * 16;
      const u16* gv = vgbase + (size_t)sr * SEQ + nx + sc * 16;
      pk0 = *(const u32x4*)(gk);
      pk1 = *(const u32x4*)(gk + 8);
      pv0 = *(const u32x4*)(gv);
      pv1 = *(const u32x4*)(gv + 8);
    }

    // edge bias from current padj (loaded last iteration)
    float eb[16];
    #pragma unroll
    for (int jt = 0; jt < 4; jt++)
      #pragma unroll
      for (int r = 0; r < 4; r++)
        eb[jt*4 + r] = fmaf(padj[jt*4 + r], Bh, Ah);
    for (int t = 0; t < mterms; t++) {
      float ct = coeff[17 + t], dt_ = coeff[33 + t], wt = coeff[49 + t*8 + h];
      #pragma unroll
      for (int jt = 0; jt < 4; jt++)
        #pragma unroll
        for (int r = 0; r < 4; r++)
          eb[jt*4 + r] = fmaf(fabsf(fmaf(padj[jt*4 + r], ct, dt_)), wt, eb[jt*4 + r]);
    }

    // issue next adjacency prefetch
    #pragma unroll
    for (int jt = 0; jt < 4; jt++)
      #pragma unroll
      for (int r = 0; r < 4; r++)
        padj[jt*4 + r] = abase[(size_t)r * SEQ + nx + jt*16 + l15];

    // S = Q K^T (scale pre-folded into Q)
    f32x4 S[4];
    #pragma unroll
    for (int jt = 0; jt < 4; jt++) {
      bf16x8 kf0 = ldfrag(&Ks[(jt*16 + l15) * 72 + q*8]);
      bf16x8 kf1 = ldfrag(&Ks[(jt*16 + l15) * 72 + 32 + q*8]);
      f32x4 s = zero;
      s = MFMA16(qf0, kf0, s);
      s = MFMA16(qf1, kf1, s);
      S[jt] = s;
    }

    // p = exp(S + edge); write P tile (per-wave, same-wave DS in-order)
    #pragma unroll
    for (int jt = 0; jt < 4; jt++) {
      #pragma unroll
      for (int r = 0; r < 4; r++) {
        float p = __expf(S[jt][r] + eb[jt*4 + r]);
        lsum[r] += p;
        psw[(q*4 + r) * 72 + jt*16 + l15] = f2bf(p);
      }
    }

    // O += P V  (P as A-operand, V as B-operand -> O in natural [i][d] layout)
    bf16x8 pf0 = ldfrag(&psw[l15 * 72 + q*8]);
    bf16x8 pf1 = ldfrag(&psw[l15 * 72 + 32 + q*8]);
    #pragma unroll
    for (int dt = 0; dt < 4; dt++) {
      bf16x8 vf0 = ldfrag(&Vs[(dt*16 + l15) * 72 + q*8]);
      bf16x8 vf1 = ldfrag(&Vs[(dt*16 + l15) * 72 + 32 + q*8]);
      O[dt] = MFMA16(pf0, vf0, O[dt]);
      O[dt] = MFMA16(pf1, vf1, O[dt]);
    }
  }

  // row sums for i = q*4+r live in the right lanes already: reduce over l15
  float rl[4];
  #pragma unroll
  for (int r = 0; r < 4; r++) {
    float v = lsum[r];
    v += __shfl_xor(v, 1);
    v += __shfl_xor(v, 2);
    v += __shfl_xor(v, 4);
    v += __shfl_xor(v, 8);
    rl[r] = 1.0f / v;
  }

  // direct store: O[i=q*4+r][d=dt*16+l15]
  #pragma unroll
  for (int dt = 0; dt < 4; dt++)
    #pragma unroll
    for (int r = 0; r < 4; r++)
      om[((size_t)b * SEQ + i0 + w*16 + q*4 + r) * EMB + h * HD + dt*16 + l15] =
          f2bf(O[dt][r] * rl[r]);
}

// ---------------------------------------------------------------- launch
extern "C" void kernel_launch(void* const* d_in, const int* in_sizes, int n_in,
                              void* d_out, int out_size, void* d_ws, size_t ws_size,
                              hipStream_t stream) {
  const float* x     = (const float*)d_in[0];
  const float* adj   = (const float*)d_in[1];
  const float* Wq    = (const float*)d_in[2];
  const float* bq    = (const float*)d_in[3];
  const float* Wk    = (const float*)d_in[4];
  const float* bk    = (const float*)d_in[5];
  const float* Wv    = (const float*)d_in[6];
  const float* bv    = (const float*)d_in[7];
  const float* Wo    = (const float*)d_in[8];
  const float* bo    = (const float*)d_in[9];
  const float* We1   = (const float*)d_in[10];
  const float* be1   = (const float*)d_in[11];
  const float* We2   = (const float*)d_in[12];
  const float* be2   = (const float*)d_in[13];
  const float* ebias = (const float*)d_in[14];
  float* out = (float*)d_out;

  char* ws = (char*)d_ws;
  u16*   xb   = (u16*)(ws + 0);          //  4 MB  x bf16
  u16*   wqkv = (u16*)(ws + 4194304);    //  1.5MB Wq|Wk|Wv bf16
  u16*   wob  = (u16*)(ws + 5767168);    //  0.5MB Wo bf16
  u16*   qh   = (u16*)(ws + 6291456);    //  4 MB  (B,H,N,64)
  u16*   kh   = (u16*)(ws + 10485760);   //  4 MB
  u16*   vh   = (u16*)(ws + 14680064);   //  4 MB
  u16*   vt   = (u16*)(ws + 18874368);   //  4 MB  (B,H,64,N)
  u16*   om   = (u16*)(ws + 23068672);   //  4 MB  (B,N,512)
  float* co   = (float*)(ws + 27262976); //  1 KB  edge coefficients
  if (ws_size < 27264000) return;

  cvt_bf16_kernel<<<2048, 256, 0, stream>>>(x, xb, NB * SEQ * EMB);
  cvt_w_kernel<<<1024, 256, 0, stream>>>(Wq, Wk, Wv, Wo, wqkv, wob);
  edge_coeff_kernel<<<1, 128, 0, stream>>>(We1, be1, We2, be2, ebias, co);
  gemm_qkv_kernel<<<dim3(12, 32), 256, 0, stream>>>(xb, wqkv, bq, bk, bv, qh, kh, vh);
  vtrans_kernel<<<dim3(32, NH, NB), 256, 0, stream>>>(vh, vt);
  flash_kernel<<<dim3(32, NH, NB), 256, 0, stream>>>(qh, kh, vt, adj, co, om);
  gemm_out_kernel<<<dim3(4, 64), 256, 0, stream>>>(om, wob, bo, out);
}

// Round 3
// 198.526 us; speedup vs baseline: 1.0781x; 1.0060x over previous
//
#include <hip/hip_runtime.h>
#include <stdint.h>

// EdgeAwareMultiHeadAttention on MI355X (gfx950) — round 3
// Changes vs round 2:
//  * flash: 512-thread blocks; waves 0-3 do j in [0,1024), waves 4-7 j in
//    [1024,2048) -> 16 waves/CU (was 8). In-block LDS combine of j-halves.
//  * flash: j-loop templated on edge-term count MT (4/8/16) -> coeff loads
//    hoisted out of the loop (runtime trip count defeated LICM before).
//  * exp -> exp2 with log2e folded into Q scale and edge coefficients.
//  * prep: cvt_x + cvt_w + edge_coeff merged into one launch.
//  * gemm_qkv retiled 64x128 (768 blocks, 3/CU).

#define SEQ 2048
#define EMB 512
#define NH  8
#define HD  64
#define NB  2
#define L2E 1.4426950408889634f

typedef unsigned int   u32;
typedef unsigned short u16;
typedef u32   u32x4  __attribute__((ext_vector_type(4)));
typedef float f32x4  __attribute__((ext_vector_type(4)));
typedef __bf16 bf16x8 __attribute__((ext_vector_type(8)));

#define MFMA16(a, b, c) __builtin_amdgcn_mfma_f32_16x16x32_bf16((a), (b), (c), 0, 0, 0)

static __device__ __forceinline__ u16 f2bf(float f) {   // RNE fp32->bf16
  return __builtin_bit_cast(u16, (__bf16)f);
}
static __device__ __forceinline__ bf16x8 ldfrag(const u16* p) {
  return __builtin_bit_cast(bf16x8, *(const u32x4*)p);
}

// ---------------------------------------------------------------- prep
// blocks [0,2048): x -> bf16 ; [2048,3072): Wq|Wk|Wv -> wqkv, Wo -> wob ;
// block 3072: edge-MLP coefficients (zero-filled to 16 slots, scaled by log2e)
__global__ void prep_kernel(const float* __restrict__ x,
                            const float* __restrict__ Wq, const float* __restrict__ Wk,
                            const float* __restrict__ Wv, const float* __restrict__ Wo,
                            const float* __restrict__ We1, const float* __restrict__ be1,
                            const float* __restrict__ We2, const float* __restrict__ be2,
                            const float* __restrict__ ebias,
                            u16* __restrict__ xb, u16* __restrict__ wqkv,
                            u16* __restrict__ wob, float* __restrict__ co) {
  const int blk = blockIdx.x, tid = threadIdx.x;
  if (blk < 2048) {
    int i = (blk * 256 + tid) * 4;
    float4 v = *(const float4*)(x + i);
    u32 lo = (u32)f2bf(v.x) | ((u32)f2bf(v.y) << 16);
    u32 hi = (u32)f2bf(v.z) | ((u32)f2bf(v.w) << 16);
    *(uint2*)(xb + i) = make_uint2(lo, hi);
  } else if (blk < 3072) {
    int i = ((blk - 2048) * 256 + tid) * 4;
    int m = i >> 18;
    int off = i & 262143;
    const float* src = (m == 0) ? Wq : ((m == 1) ? Wk : ((m == 2) ? Wv : Wo));
    u16* dst = (m < 3) ? (wqkv + (size_t)m * 262144) : wob;
    float4 v = *(const float4*)(src + off);
    u32 lo = (u32)f2bf(v.x) | ((u32)f2bf(v.y) << 16);
    u32 hi = (u32)f2bf(v.z) | ((u32)f2bf(v.w) << 16);
    *(uint2*)(dst + off) = make_uint2(lo, hi);
  } else {
    const int e = tid & 15, h = tid >> 4;
    if (tid < 128) {                     // zero-fill all 16 slots
      co[49 + e * 8 + h] = 0.0f;
      if (h == 0) { co[17 + e] = 0.0f; co[33 + e] = 0.0f; }
    }
    __syncthreads();
    if (tid < 128) {
      float w1 = We1[e], b1 = be1[e], w2 = We2[h * 16 + e];
      float u0 = b1, u1 = w1 + b1;
      bool on  = (u0 >= 0.0f) && (u1 >= 0.0f);
      bool off = (u0 <= 0.0f) && (u1 <= 0.0f);
      bool crossing = (!on) && (!off);
      float ca = on ? (w2 * b1) : (crossing ? 0.5f * w2 * b1 : 0.0f);
      float cb = on ? (w2 * w1) : (crossing ? 0.5f * w2 * w1 : 0.0f);
      #pragma unroll
      for (int d = 1; d < 16; d <<= 1) { ca += __shfl_xor(ca, d); cb += __shfl_xor(cb, d); }
      if (e == 0) { co[h] = (be2[h] + ca) * L2E; co[8 + h] = (ebias[h] + cb) * L2E; }
      unsigned long long msk = __ballot(crossing);
      int midx = __popcll(msk & 0xFFFFull & ((1ull << e) - 1ull));
      int mcnt = __popcll(msk & 0xFFFFull);
      if (crossing) {
        co[49 + midx * 8 + h] = 0.5f * w2 * L2E;
        if (h == 0) { co[17 + midx] = w1; co[33 + midx] = b1; }
      }
      if (tid == 0) ((int*)co)[16] = mcnt;
    }
  }
}

// ---------------------------------------------------------------- k1: QKV GEMM 64x128
#define LDA 40
__global__ __launch_bounds__(256) void gemm_qkv_kernel(
    const u16* __restrict__ A, const u16* __restrict__ Bm,
    const float* __restrict__ bq, const float* __restrict__ bk, const float* __restrict__ bv,
    u16* __restrict__ qh, u16* __restrict__ kh, u16* __restrict__ vh)
{
  __shared__ u16 As[64 * LDA];
  __shared__ u16 Bs[128 * LDA];
  const int tid = threadIdx.x;
  const int lane = tid & 63, w = tid >> 6;
  const int q = lane >> 4, l15 = lane & 15;
  const int m0 = blockIdx.y * 64;
  const int n0 = blockIdx.x * 128;

  f32x4 acc[4][2];
  f32x4 zero = {0.f, 0.f, 0.f, 0.f};
  #pragma unroll
  for (int i = 0; i < 4; i++) { acc[i][0] = zero; acc[i][1] = zero; }

  const bool isA = tid < 128;
  const int arow = tid >> 1, ahalf = tid & 1;
  const int brow = tid - 128;
  const u16* ga = A  + (size_t)(m0 + arow) * EMB + ahalf * 16;
  const u16* gb = Bm + (size_t)(n0 + brow) * EMB;
  u16* la = &As[arow * LDA + ahalf * 16];
  u16* lb = &Bs[brow * LDA];

  u32x4 p0, p1, p2, p3;
  if (isA) {
    p0 = *(const u32x4*)(ga); p1 = *(const u32x4*)(ga + 8); ga += 32;
  } else {
    p0 = *(const u32x4*)(gb);      p1 = *(const u32x4*)(gb + 8);
    p2 = *(const u32x4*)(gb + 16); p3 = *(const u32x4*)(gb + 24); gb += 32;
  }

  for (int k0 = 0; k0 < EMB; k0 += 32) {
    __syncthreads();
    if (isA) { *(u32x4*)(la) = p0; *(u32x4*)(la + 8) = p1; }
    else {
      *(u32x4*)(lb)      = p0; *(u32x4*)(lb + 8)  = p1;
      *(u32x4*)(lb + 16) = p2; *(u32x4*)(lb + 24) = p3;
    }
    __syncthreads();
    if (k0 + 32 < EMB) {
      if (isA) { p0 = *(const u32x4*)(ga); p1 = *(const u32x4*)(ga + 8); ga += 32; }
      else {
        p0 = *(const u32x4*)(gb);      p1 = *(const u32x4*)(gb + 8);
        p2 = *(const u32x4*)(gb + 16); p3 = *(const u32x4*)(gb + 24); gb += 32;
      }
    }
    bf16x8 af[4], bfr[2];
    #pragma unroll
    for (int mi = 0; mi < 4; mi++)
      af[mi] = ldfrag(&As[(mi*16 + l15) * LDA + q*8]);
    #pragma unroll
    for (int ni = 0; ni < 2; ni++)
      bfr[ni] = ldfrag(&Bs[(w*32 + ni*16 + l15) * LDA + q*8]);
    #pragma unroll
    for (int mi = 0; mi < 4; mi++)
      #pragma unroll
      for (int ni = 0; ni < 2; ni++)
        acc[mi][ni] = MFMA16(af[mi], bfr[ni], acc[mi][ni]);
  }

  const int mat = n0 >> 9;                // 0:Q 1:K 2:V
  const float* bias = (mat == 0) ? bq : ((mat == 1) ? bk : bv);
  u16* dst = (mat == 0) ? qh : ((mat == 1) ? kh : vh);
  const float mul = (mat == 0) ? 0.125f * L2E : 1.0f;  // Q carries scale*log2e

  #pragma unroll
  for (int mi = 0; mi < 4; mi++) {
    int rowb = m0 + mi*16 + q*4;
    #pragma unroll
    for (int ni = 0; ni < 2; ni++) {
      int col = n0 + w*32 + ni*16 + l15;
      int oo = col & 511;
      float bsv = bias[oo];
      int hh = oo >> 6, dd = oo & 63;
      #pragma unroll
      for (int r = 0; r < 4; r++) {
        int grow = rowb + r;
        int b_ = grow >> 11, n_ = grow & 2047;
        float val = (acc[mi][ni][r] + bsv) * mul;
        dst[((size_t)(b_ * NH + hh) * SEQ + n_) * HD + dd] = f2bf(val);
      }
    }
  }
}

// ---------------------------------------------------------------- k3: out GEMM 64x128
__global__ __launch_bounds__(256) void gemm_out_kernel(
    const u16* __restrict__ A, const u16* __restrict__ Bm,
    const float* __restrict__ bo, float* __restrict__ out)
{
  __shared__ u16 As[64 * LDA];
  __shared__ u16 Bs[128 * LDA];
  const int tid = threadIdx.x;
  const int lane = tid & 63, w = tid >> 6;
  const int q = lane >> 4, l15 = lane & 15;
  const int m0 = blockIdx.y * 64;
  const int n0 = blockIdx.x * 128;

  f32x4 acc[4][2];
  f32x4 zero = {0.f, 0.f, 0.f, 0.f};
  #pragma unroll
  for (int i = 0; i < 4; i++) { acc[i][0] = zero; acc[i][1] = zero; }

  const bool isA = tid < 128;
  const int arow = tid >> 1, ahalf = tid & 1;
  const int brow = tid - 128;
  const u16* ga = A  + (size_t)(m0 + arow) * EMB + ahalf * 16;
  const u16* gb = Bm + (size_t)(n0 + brow) * EMB;
  u16* la = &As[arow * LDA + ahalf * 16];
  u16* lb = &Bs[brow * LDA];

  u32x4 p0, p1, p2, p3;
  if (isA) {
    p0 = *(const u32x4*)(ga); p1 = *(const u32x4*)(ga + 8); ga += 32;
  } else {
    p0 = *(const u32x4*)(gb);      p1 = *(const u32x4*)(gb + 8);
    p2 = *(const u32x4*)(gb + 16); p3 = *(const u32x4*)(gb + 24); gb += 32;
  }

  for (int k0 = 0; k0 < EMB; k0 += 32) {
    __syncthreads();
    if (isA) { *(u32x4*)(la) = p0; *(u32x4*)(la + 8) = p1; }
    else {
      *(u32x4*)(lb)      = p0; *(u32x4*)(lb + 8)  = p1;
      *(u32x4*)(lb + 16) = p2; *(u32x4*)(lb + 24) = p3;
    }
    __syncthreads();
    if (k0 + 32 < EMB) {
      if (isA) { p0 = *(const u32x4*)(ga); p1 = *(const u32x4*)(ga + 8); ga += 32; }
      else {
        p0 = *(const u32x4*)(gb);      p1 = *(const u32x4*)(gb + 8);
        p2 = *(const u32x4*)(gb + 16); p3 = *(const u32x4*)(gb + 24); gb += 32;
      }
    }
    bf16x8 af[4], bfr[2];
    #pragma unroll
    for (int mi = 0; mi < 4; mi++)
      af[mi] = ldfrag(&As[(mi*16 + l15) * LDA + q*8]);
    #pragma unroll
    for (int ni = 0; ni < 2; ni++)
      bfr[ni] = ldfrag(&Bs[(w*32 + ni*16 + l15) * LDA + q*8]);
    #pragma unroll
    for (int mi = 0; mi < 4; mi++)
      #pragma unroll
      for (int ni = 0; ni < 2; ni++)
        acc[mi][ni] = MFMA16(af[mi], bfr[ni], acc[mi][ni]);
  }

  #pragma unroll
  for (int mi = 0; mi < 4; mi++) {
    int rowb = m0 + mi*16 + q*4;
    #pragma unroll
    for (int ni = 0; ni < 2; ni++) {
      int col = n0 + w*32 + ni*16 + l15;
      float bsv = bo[col];
      #pragma unroll
      for (int r = 0; r < 4; r++)
        out[(size_t)(rowb + r) * EMB + col] = acc[mi][ni][r] + bsv;
    }
  }
}

// ---------------------------------------------------------------- k1b: V transpose
__global__ __launch_bounds__(256) void vtrans_kernel(const u16* __restrict__ vh, u16* __restrict__ vt) {
  __shared__ u16 Ts[64 * 72];
  const int b = blockIdx.z, h = blockIdx.y, j0 = blockIdx.x * 64;
  const int t = threadIdx.x;
  const u16* src = vh + ((size_t)(b * NH + h) * SEQ + j0) * HD;
  {
    int r = t >> 2, c = t & 3;
    *(u32x4*)&Ts[r*72 + c*16]     = *(const u32x4*)(src + r*HD + c*16);
    *(u32x4*)&Ts[r*72 + c*16 + 8] = *(const u32x4*)(src + r*HD + c*16 + 8);
  }
  __syncthreads();
  int d = t >> 2, jc = t & 3;
  u32 wv[8];
  #pragma unroll
  for (int p = 0; p < 8; p++) {
    u32 lo = Ts[(jc*16 + 2*p    ) * 72 + d];
    u32 hi = Ts[(jc*16 + 2*p + 1) * 72 + d];
    wv[p] = lo | (hi << 16);
  }
  u16* dst = vt + ((size_t)(b * NH + h) * HD + d) * SEQ + j0 + jc * 16;
  u32x4 w0 = {wv[0], wv[1], wv[2], wv[3]};
  u32x4 w1 = {wv[4], wv[5], wv[6], wv[7]};
  *(u32x4*)(dst)     = w0;
  *(u32x4*)(dst + 8) = w1;
}

// ---------------------------------------------------------------- k2: flash + edge
// 512 threads = 8 waves. Wave w: i-rows (w&3)*16.., j-half (w>>2)*1024.
// smem layout (u16): Ks [2][64][72] | Vs [2][64][72] | Ps [8][16][72]
template<int MT>
__device__ __forceinline__ void flash_body(
    u16* __restrict__ smem,
    const u16* __restrict__ qh, const u16* __restrict__ kh, const u16* __restrict__ vt,
    const float* __restrict__ adj, const float* __restrict__ coeff, u16* __restrict__ om)
{
  u16* Ks = smem;
  u16* Vs = smem + 9216;
  u16* Ps = smem + 18432;

  const int tid = threadIdx.x, lane = tid & 63, w = tid >> 6;
  const int q = lane >> 4, l15 = lane & 15;
  const int i0 = blockIdx.x * 64;
  const int h = blockIdx.y, b = blockIdx.z;
  const int bh = b * NH + h;
  const int jhalf = w >> 2, wrow = (w & 3) * 16;
  const int jbase = jhalf * 1024;

  const float Ah = coeff[h], Bh = coeff[8 + h];
  float ctr[MT > 0 ? MT : 1], dtr[MT > 0 ? MT : 1], wtr[MT > 0 ? MT : 1];
  #pragma unroll
  for (int t = 0; t < MT; t++) {
    ctr[t] = coeff[17 + t];
    dtr[t] = coeff[33 + t];
    wtr[t] = coeff[49 + t * 8 + h];
  }

  const u16* qbase = qh + ((size_t)bh * SEQ + i0 + wrow + l15) * HD + q * 8;
  bf16x8 qf0 = ldfrag(qbase);
  bf16x8 qf1 = ldfrag(qbase + 32);

  f32x4 O[4];
  f32x4 zero = {0.f, 0.f, 0.f, 0.f};
  #pragma unroll
  for (int dt = 0; dt < 4; dt++) O[dt] = zero;
  float lsum[4] = {0.f, 0.f, 0.f, 0.f};

  const float* abase = adj + ((size_t)b * SEQ + i0 + wrow + q * 4) * SEQ + jbase;

  // staging: 512 threads cover 2 K-tiles + 2 V-tiles of 64x64 bf16
  const int shalf = tid >> 8, t8 = tid & 255;
  const int sr = t8 >> 2, sc = t8 & 3;
  const u16* kgs = kh + (size_t)bh * SEQ * HD + ((size_t)(shalf * 1024) + sr) * HD + sc * 16;
  const u16* vgs = vt + (size_t)bh * HD * SEQ + (size_t)sr * SEQ + shalf * 1024 + sc * 16;
  u16* kls = &Ks[(shalf * 64 + sr) * 72 + sc * 16];
  u16* vls = &Vs[(shalf * 64 + sr) * 72 + sc * 16];

  u16* psw = &Ps[w * 16 * 72];

  // prologue prefetch (tile 0 of this thread's staged half)
  u32x4 pk0 = *(const u32x4*)(kgs);
  u32x4 pk1 = *(const u32x4*)(kgs + 8);
  u32x4 pv0 = *(const u32x4*)(vgs);
  u32x4 pv1 = *(const u32x4*)(vgs + 8);
  float padj[16];
  #pragma unroll
  for (int jt = 0; jt < 4; jt++)
    #pragma unroll
    for (int r = 0; r < 4; r++)
      padj[jt * 4 + r] = abase[(size_t)r * SEQ + jt * 16 + l15];

  for (int it = 0; it < 16; it++) {
    __syncthreads();
    *(u32x4*)(kls)     = pk0;
    *(u32x4*)(kls + 8) = pk1;
    *(u32x4*)(vls)     = pv0;
    *(u32x4*)(vls + 8) = pv1;
    __syncthreads();

    const int nxo = ((it + 1) & 15) * 64;      // next j-offset within half (wraps, harmless)
    pk0 = *(const u32x4*)(kgs + (size_t)nxo * HD);
    pk1 = *(const u32x4*)(kgs + (size_t)nxo * HD + 8);
    pv0 = *(const u32x4*)(vgs + nxo);
    pv1 = *(const u32x4*)(vgs + nxo + 8);

    // S = Q K^T (Q carries 0.125*log2e)
    f32x4 S[4];
    #pragma unroll
    for (int jt = 0; jt < 4; jt++) {
      bf16x8 kf0 = ldfrag(&Ks[(jhalf * 64 + jt * 16 + l15) * 72 + q * 8]);
      bf16x8 kf1 = ldfrag(&Ks[(jhalf * 64 + jt * 16 + l15) * 72 + 32 + q * 8]);
      f32x4 s = zero;
      s = MFMA16(qf0, kf0, s);
      s = MFMA16(qf1, kf1, s);
      S[jt] = s;
    }

    // edge bias (log2 domain), overlapped with MFMA latency
    float eb[16];
    #pragma unroll
    for (int u = 0; u < 16; u++)
      eb[u] = fmaf(padj[u], Bh, Ah);
    #pragma unroll
    for (int t = 0; t < MT; t++)
      #pragma unroll
      for (int u = 0; u < 16; u++)
        eb[u] = fmaf(fabsf(fmaf(padj[u], ctr[t], dtr[t])), wtr[t], eb[u]);

    // adjacency prefetch for next tile
    #pragma unroll
    for (int jt = 0; jt < 4; jt++)
      #pragma unroll
      for (int r = 0; r < 4; r++)
        padj[jt * 4 + r] = abase[(size_t)r * SEQ + nxo + jt * 16 + l15];

    // p = 2^(S + eb) = exp(orig)
    #pragma unroll
    for (int jt = 0; jt < 4; jt++) {
      #pragma unroll
      for (int r = 0; r < 4; r++) {
        float p = __builtin_amdgcn_exp2f(S[jt][r] + eb[jt * 4 + r]);
        lsum[r] += p;
        psw[(q * 4 + r) * 72 + jt * 16 + l15] = f2bf(p);
      }
    }

    // O += P V
    bf16x8 pf0 = ldfrag(&psw[l15 * 72 + q * 8]);
    bf16x8 pf1 = ldfrag(&psw[l15 * 72 + 32 + q * 8]);
    #pragma unroll
    for (int dt = 0; dt < 4; dt++) {
      bf16x8 vf0 = ldfrag(&Vs[(jhalf * 64 + dt * 16 + l15) * 72 + q * 8]);
      bf16x8 vf1 = ldfrag(&Vs[(jhalf * 64 + dt * 16 + l15) * 72 + 32 + q * 8]);
      O[dt] = MFMA16(pf0, vf0, O[dt]);
      O[dt] = MFMA16(pf1, vf1, O[dt]);
    }
  }

  // reduce lsum across the 16 lanes of each quad-group (per half)
  #pragma unroll
  for (int r = 0; r < 4; r++) {
    float v = lsum[r];
    v += __shfl_xor(v, 1);
    v += __shfl_xor(v, 2);
    v += __shfl_xor(v, 4);
    v += __shfl_xor(v, 8);
    lsum[r] = v;
  }

  // combine halves: upper waves (j-half 1) publish O,l via LDS (padded stride-5 f32x4)
  __syncthreads();
  f32x4* Of = (f32x4*)smem;                       // [(w&3)*64+lane]*5 + dt
  f32x4* Lf = (f32x4*)((float*)smem + 5120);      // [(w&3)*64+lane]
  if (w >= 4) {
    const int bi = ((w & 3) * 64 + lane);
    #pragma unroll
    for (int dt = 0; dt < 4; dt++) Of[bi * 5 + dt] = O[dt];
    f32x4 lv = {lsum[0], lsum[1], lsum[2], lsum[3]};
    Lf[bi] = lv;
  }
  __syncthreads();
  if (w < 4) {
    const int bi = (w * 64 + lane);
    f32x4 lv = Lf[bi];
    float rl[4];
    #pragma unroll
    for (int r = 0; r < 4; r++) rl[r] = 1.0f / (lsum[r] + lv[r]);
    #pragma unroll
    for (int dt = 0; dt < 4; dt++) {
      f32x4 ov = Of[bi * 5 + dt];
      #pragma unroll
      for (int r = 0; r < 4; r++) {
        float val = (O[dt][r] + ov[r]) * rl[r];
        om[((size_t)b * SEQ + i0 + wrow + q * 4 + r) * EMB + h * HD + dt * 16 + l15] = f2bf(val);
      }
    }
  }
}

__global__ __launch_bounds__(512) void flash_kernel(
    const u16* __restrict__ qh, const u16* __restrict__ kh, const u16* __restrict__ vt,
    const float* __restrict__ adj, const float* __restrict__ coeff, u16* __restrict__ om)
{
  __shared__ __align__(16) u16 smem[27648];   // 55296 B
  const int mt = ((const int*)coeff)[16];     // uniform
  if (mt <= 4)      flash_body<4>(smem, qh, kh, vt, adj, coeff, om);
  else if (mt <= 8) flash_body<8>(smem, qh, kh, vt, adj, coeff, om);
  else              flash_body<16>(smem, qh, kh, vt, adj, coeff, om);
}

// ---------------------------------------------------------------- launch
extern "C" void kernel_launch(void* const* d_in, const int* in_sizes, int n_in,
                              void* d_out, int out_size, void* d_ws, size_t ws_size,
                              hipStream_t stream) {
  const float* x     = (const float*)d_in[0];
  const float* adj   = (const float*)d_in[1];
  const float* Wq    = (const float*)d_in[2];
  const float* bq    = (const float*)d_in[3];
  const float* Wk    = (const float*)d_in[4];
  const float* bk    = (const float*)d_in[5];
  const float* Wv    = (const float*)d_in[6];
  const float* bv    = (const float*)d_in[7];
  const float* Wo    = (const float*)d_in[8];
  const float* bo    = (const float*)d_in[9];
  const float* We1   = (const float*)d_in[10];
  const float* be1   = (const float*)d_in[11];
  const float* We2   = (const float*)d_in[12];
  const float* be2   = (const float*)d_in[13];
  const float* ebias = (const float*)d_in[14];
  float* out = (float*)d_out;

  char* ws = (char*)d_ws;
  u16*   xb   = (u16*)(ws + 0);          //  4 MB  x bf16
  u16*   wqkv = (u16*)(ws + 4194304);    //  1.5MB Wq|Wk|Wv bf16
  u16*   wob  = (u16*)(ws + 5767168);    //  0.5MB Wo bf16
  u16*   qh   = (u16*)(ws + 6291456);    //  4 MB  (B,H,N,64)
  u16*   kh   = (u16*)(ws + 10485760);   //  4 MB
  u16*   vh   = (u16*)(ws + 14680064);   //  4 MB
  u16*   vt   = (u16*)(ws + 18874368);   //  4 MB  (B,H,64,N)
  u16*   om   = (u16*)(ws + 23068672);   //  4 MB  (B,N,512)
  float* co   = (float*)(ws + 27262976); //  1 KB  edge coefficients
  if (ws_size < 27264000) return;

  prep_kernel<<<3073, 256, 0, stream>>>(x, Wq, Wk, Wv, Wo, We1, be1, We2, be2, ebias,
                                        xb, wqkv, wob, co);
  gemm_qkv_kernel<<<dim3(12, 64), 256, 0, stream>>>(xb, wqkv, bq, bk, bv, qh, kh, vh);
  vtrans_kernel<<<dim3(32, NH, NB), 256, 0, stream>>>(vh, vt);
  flash_kernel<<<dim3(32, NH, NB), 512, 0, stream>>>(qh, kh, vt, adj, co, om);
  gemm_out_kernel<<<dim3(4, 64), 256, 0, stream>>>(om, wob, bo, out);
}